// Round 5
// baseline (84.567 us; speedup 1.0000x reference)
//
#include <hip/hip_runtime.h>

// Fourier head: B=512, P=1024, K=64.
// out[b,p] = a0/(2P) + sum_k pa[b,k]*cos(c*x[b,p]*k) + pb[b,k]*sin(c*x[b,p]*k)
// pa = x @ a, pb = x @ b, c = 2*pi/P.  Inputs f32, output f32 (R0-R2 triangulated).
//
// R3/R4: fused kernel ~6.5us; dur_us ~72 dominated by ~65us harness fixed cost
// (256MB d_ws re-poison fill at 84% HBM + restores). Fused stage B streams all
// of a+b (512KB) through EVERY CU's L1/L2 port (~3.9us) -- structural.
// R5: split pipeline. K1: partial GEMM, 256 blocks each reading only its
// unique 32KB a/b slice, writes split-P partials pw[512][16][128] (4MB in ws).
// K2: 512 blocks (1 row), 16-way reduce + Chebyshev stage C.
// Model: K1 ~1.0us + K2 ~1.8us vs fused ~6.5us.

constexpr int PN = 1024;
constexpr int KN = 64;

// ---------- Kernel 1: partial GEMM over (p-chunk, b-tile) ----------
// grid (16 pc, 16 bt), 256 threads. Block reads a/b[p0:p0+64][0:64] (32KB
// unique) + x[b0:b0+32][p0:p0+64] (8KB). Writes pw[b][pc][2k+{0,1}] partials.
__global__ __launch_bounds__(256) void k_partial(
    const float* __restrict__ x,
    const float* __restrict__ a,
    const float* __restrict__ bco,
    float* __restrict__ pw)
{
    __shared__ float xs[32][64];             // 8 KB x-tile, b-major

    const int t = threadIdx.x;
    const int pc = blockIdx.x;               // p-chunk: p in [64*pc, 64*pc+64)
    const int bt = blockIdx.y;               // b-tile:  b in [32*bt, 32*bt+32)
    const int p0 = pc * 64;
    const int b0 = bt * 32;

    // Stage x-tile: 16 lanes cover one 256B row segment (float4, coalesced).
    {
        const int c = t & 15, row = t >> 4;
        #pragma unroll
        for (int h = 0; h < 2; ++h) {
            const int r = row + 16 * h;
            const float4 v = *(const float4*)(x + (size_t)(b0 + r) * PN + p0 + 4 * c);
            xs[r][4 * c + 0] = v.x; xs[r][4 * c + 1] = v.y;
            xs[r][4 * c + 2] = v.z; xs[r][4 * c + 3] = v.w;
        }
    }
    __syncthreads();

    // Thread (kg = t&15, bg = t>>4): outputs k4 = 4*kg (a and b), rows 2bg,2bg+1.
    // a/b float4 loads: 16 unique 16B segments per wave = 256B contiguous
    // (2-4 cache lines, same-address lanes deduped by the coalescer).
    const int kg = t & 15;
    const int bg = t >> 4;
    float sa[2][4] = {{0.f}}, sb[2][4] = {{0.f}};
    #pragma unroll 4
    for (int i = 0; i < 64; ++i) {
        const int p = p0 + i;
        const float4 av = *(const float4*)(a   + (size_t)p * KN + 4 * kg);
        const float4 bv = *(const float4*)(bco + (size_t)p * KN + 4 * kg);
        #pragma unroll
        for (int r = 0; r < 2; ++r) {
            const float xv = xs[2 * bg + r][i];   // 4 unique addrs/wave (bcast)
            sa[r][0] = fmaf(xv, av.x, sa[r][0]);
            sa[r][1] = fmaf(xv, av.y, sa[r][1]);
            sa[r][2] = fmaf(xv, av.z, sa[r][2]);
            sa[r][3] = fmaf(xv, av.w, sa[r][3]);
            sb[r][0] = fmaf(xv, bv.x, sb[r][0]);
            sb[r][1] = fmaf(xv, bv.y, sb[r][1]);
            sb[r][2] = fmaf(xv, bv.z, sb[r][2]);
            sb[r][3] = fmaf(xv, bv.w, sb[r][3]);
        }
    }

    // pw[b][pc][2k+{0,1}]: interleaved (pa,pb) pairs -> float2 stores.
    #pragma unroll
    for (int r = 0; r < 2; ++r) {
        float* dst = pw + (((size_t)(b0 + 2 * bg + r) * 16 + pc) * 128) + 8 * kg;
        #pragma unroll
        for (int j = 0; j < 4; ++j) {
            float2 v; v.x = sa[r][j]; v.y = sb[r][j];
            *(float2*)(dst + 2 * j) = v;
        }
    }
}

// ---------- Kernel 2: reduce partials + Chebyshev stage C ----------
// grid 512 (1 batch row per block), 256 threads, 4 points/thread.
__global__ __launch_bounds__(256) void k_out(
    const float* __restrict__ x,
    const float* __restrict__ pw,
    const float* __restrict__ a0,
    float* __restrict__ out)
{
    __shared__ float spab[2 * KN];           // interleaved pa/pb

    const int t = threadIdx.x;
    const int b = blockIdx.x;

    // Reduce 16 p-chunks: row's partials are 8KB contiguous; per-inst 64
    // lanes read 256B contiguous (coalesced).
    if (t < 128) {
        const float* src = pw + (size_t)b * (16 * 128) + t;
        float s = 0.f;
        #pragma unroll
        for (int pc = 0; pc < 16; ++pc) s += src[pc * 128];
        spab[t] = s;
    }
    __syncthreads();

    // Stage C: Chebyshev recurrence, x straight from global (float4).
    const float4 xv4 = ((const float4*)(x + (size_t)b * PN))[t];
    const float xv[4] = {xv4.x, xv4.y, xv4.z, xv4.w};
    const float c0 = a0[0] * (1.0f / (2.0f * (float)PN));
    const float tp = (float)(6.283185307179586 / (double)PN);  // 2*pi/P

    float cm1[4], sm1[4], cm2[4], sm2[4], t2[4], acc[4];
    const float pa0 = spab[0];
    const float pa1 = spab[2];
    const float pb1 = spab[3];
    #pragma unroll
    for (int j = 0; j < 4; ++j) {
        const float th = tp * xv[j];
        float c1, s1;
        __sincosf(th, &s1, &c1);
        t2[j]  = c1 + c1;
        cm2[j] = 1.f; sm2[j] = 0.f;          // k=0
        cm1[j] = c1;  sm1[j] = s1;           // k=1
        acc[j] = fmaf(pa1, c1, fmaf(pb1, s1, c0 + pa0));
    }
    #pragma unroll 8
    for (int k = 2; k < KN; ++k) {
        const float2 pk = *(const float2*)&spab[2 * k];  // ds_read_b64 bcast
        #pragma unroll
        for (int j = 0; j < 4; ++j) {
            const float ck = fmaf(t2[j], cm1[j], -cm2[j]);
            const float sk = fmaf(t2[j], sm1[j], -sm2[j]);
            acc[j] = fmaf(pk.x, ck, acc[j]);
            acc[j] = fmaf(pk.y, sk, acc[j]);
            cm2[j] = cm1[j]; cm1[j] = ck;
            sm2[j] = sm1[j]; sm1[j] = sk;
        }
    }
    float4 o; o.x = acc[0]; o.y = acc[1]; o.z = acc[2]; o.w = acc[3];
    ((float4*)(out + (size_t)b * PN))[t] = o;
}

extern "C" void kernel_launch(void* const* d_in, const int* in_sizes, int n_in,
                              void* d_out, int out_size, void* d_ws, size_t ws_size,
                              hipStream_t stream) {
    const float* x  = (const float*)d_in[0];
    const float* a  = (const float*)d_in[1];
    const float* b  = (const float*)d_in[2];
    const float* a0 = (const float*)d_in[3];
    float* out = (float*)d_out;
    float* pw  = (float*)d_ws;               // 512*16*128*4 = 4 MB

    k_partial<<<dim3(16, 16), dim3(256), 0, stream>>>(x, a, b, pw);
    k_out<<<dim3(512), dim3(256), 0, stream>>>(x, pw, a0, out);
}